// Round 7
// baseline (188.137 us; speedup 1.0000x reference)
//
#include <hip/hip_runtime.h>

// LeakySNN fused: out[b] = b2 + sum_h spksum(x1[b,h]) * W2[h]
// R7: fp16 two-term split hoisted into a prelude kernel that writes xh/xl/
//     wh/wl into d_ws in LDS-image order (per 128-row band, per 32-k tile,
//     granule P(row,q)=row*4+(q^((row>>2)&3)) — XOR swizzle baked into the
//     array). Main kernel: global_load_lds(16B) staging with ZERO VALU,
//     conflict-free ds_read_b128 fragments (2-way max), 48 MFMA/tile,
//     then R6's breakpoint-staircase epilogue. init+bp+splits = one prep
//     dispatch. Falls back to the R6 kernel if ws_size < ~35 MB.

#define NI 256
#define NH 1024
#define NSTEPS 25
#define BT 128
#define BK 32
#define NTILES (NI / BK)
#define RW 40   // fallback (R6) LDS row width in halfs

typedef _Float16 half8 __attribute__((ext_vector_type(8)));
typedef _Float16 half4 __attribute__((ext_vector_type(4)));
typedef float float4v __attribute__((ext_vector_type(4)));

__device__ __forceinline__ unsigned f2k(float f) {
    unsigned u = __float_as_uint(f);
    return (u >> 31) ? ~u : (u | 0x80000000u);
}
__device__ __forceinline__ float k2f(unsigned k) {
    unsigned u = (k & 0x80000000u) ? (k & 0x7FFFFFFFu) : ~k;
    return __uint_as_float(u);
}

// 25-step LIF count, exact reference-matching arithmetic (R4/R6).
__device__ __forceinline__ int lif_count(float x1, float beta, float th) {
    float mem = 0.f;
    float spk = (0.f > th) ? 1.f : 0.f;
    int c = 0;
#pragma unroll
    for (int t = 0; t < NSTEPS; t++) {
        mem = fmaf(spk, -th, fmaf(beta, mem, x1));
        spk = (mem > th) ? 1.f : 0.f;
        c += (mem > th);
    }
    return c;
}

__device__ __forceinline__ void async_load16(const _Float16* g, _Float16* l) {
    __builtin_amdgcn_global_load_lds(
        (const __attribute__((address_space(1))) void*)g,
        (__attribute__((address_space(3))) void*)l, 16, 0, 0);
}

__device__ __forceinline__ void split8(const float* src, half8* hi, half8* lo) {
    float4v a = *(const float4v*)src;
    float4v b = *(const float4v*)(src + 4);
#pragma unroll
    for (int e = 0; e < 4; e++) {
        _Float16 h = (_Float16)a[e];
        (*hi)[e] = h;
        (*lo)[e] = (_Float16)(a[e] - (float)h);
        h = (_Float16)b[e];
        (*hi)[e + 4] = h;
        (*lo)[e + 4] = (_Float16)(b[e] - (float)h);
    }
}

// ===================== fast path =====================

// One dispatch: x-split (B/8 blocks) | W-split (128) | bp (100) | init (B/256).
// Split arrays are in "LDS image" order: granule G = (band*8+kt)*512 + g,
// g = row*4 + p, logical k-chunk q = p ^ ((row>>2)&3); granule = 8 halfs.
__global__ __launch_bounds__(256) void snn_prep(
    const float* __restrict__ x, const float* __restrict__ W1,
    const float* __restrict__ thr, const float* __restrict__ betap,
    const float* __restrict__ b2, float* __restrict__ out,
    float* __restrict__ bp, _Float16* __restrict__ whp, _Float16* __restrict__ wlp,
    _Float16* __restrict__ xhp, _Float16* __restrict__ xlp, int B)
{
    const int tid = threadIdx.x;
    const int XB = B / 8;            // x-split blocks
    int bid = blockIdx.x;

    if (bid < XB) {                  // ---- x split ----
        const int G = bid * 256 + tid;
        const int band = G >> 12;    // 8 kt * 512 granules per 128-row band
        const int rem = G & 4095;
        const int kt = rem >> 9, g = rem & 511;
        const int row = g >> 2, p = g & 3;
        const int q = p ^ ((row >> 2) & 3);
        const float* src = x + (size_t)(band * 128 + row) * NI + kt * 32 + q * 8;
        half8 hi, lo;
        split8(src, &hi, &lo);
        ((half8*)xhp)[G] = hi;
        ((half8*)xlp)[G] = lo;
        return;
    }
    bid -= XB;
    if (bid < 128) {                 // ---- W1 split ----
        const int G = bid * 256 + tid;   // < 32768
        const int band = G >> 12;
        const int rem = G & 4095;
        const int kt = rem >> 9, g = rem & 511;
        const int row = g >> 2, p = g & 3;
        const int q = p ^ ((row >> 2) & 3);
        const float* src = W1 + (size_t)(band * 128 + row) * NI + kt * 32 + q * 8;
        half8 hi, lo;
        split8(src, &hi, &lo);
        ((half8*)whp)[G] = hi;
        ((half8*)wlp)[G] = lo;
        return;
    }
    bid -= 128;
    if (bid < 100) {                 // ---- breakpoints ----
        const int idx = bid * 256 + tid;     // exactly 25600
        const int h = idx / NSTEPS;
        const int k = idx % NSTEPS + 1;      // target count 1..25
        const float th = thr[h];
        float beta = betap[0];
        beta = beta < 0.f ? 0.f : (beta > 1.f ? 1.f : beta);
        unsigned lo = f2k(-3.0e38f), hi = f2k(3.0e38f);
        float res;
        if (lif_count(k2f(hi), beta, th) < k) {
            res = 3.0e38f;
        } else if (lif_count(k2f(lo), beta, th) >= k) {
            res = -3.0e38f;
        } else {
#pragma unroll 1
            for (int it = 0; it < 32; it++) {
                unsigned mid = lo + ((hi - lo) >> 1);
                if (lif_count(k2f(mid), beta, th) >= k) hi = mid; else lo = mid;
            }
            res = k2f(hi);
        }
        bp[(k - 1) * NH + h] = res;
        return;
    }
    bid -= 100;
    {                                // ---- out init ----
        const int i = bid * 256 + tid;
        if (i < B) out[i] = b2[0];
    }
}

__global__ __launch_bounds__(256, 4) void snn_main_fast(
    const _Float16* __restrict__ xhp, const _Float16* __restrict__ xlp,
    const _Float16* __restrict__ whp, const _Float16* __restrict__ wlp,
    const float* __restrict__ b1, const float* __restrict__ W2,
    const float* __restrict__ bp, float* __restrict__ out)
{
    __shared__ __align__(16) _Float16 lds[4 * 4096];   // 32 KB
    _Float16* xh = lds;
    _Float16* xl = lds + 4096;
    _Float16* wh = lds + 8192;
    _Float16* wl = lds + 12288;

    const int tid  = threadIdx.x;
    const int w    = tid >> 6;
    const int lane = tid & 63;
    const int col  = lane & 15;
    const int quad = lane >> 4;
    const int wbb  = (w >> 1) * 64;
    const int whh  = (w & 1) * 64;
    const int band_x = blockIdx.x;     // b band
    const int band_w = blockIdx.y;     // h band
    const int b0 = band_x * BT;
    const int h0 = band_w * BT;

    // staging: granule per thread g = w*64 + lane + 256*r (wave-uniform base)
    const int gbase = w * 64;          // + lane implicit in HW
    const half8* xsrc_h = (const half8*)xhp + (size_t)band_x * (8 * 512);
    const half8* xsrc_l = (const half8*)xlp + (size_t)band_x * (8 * 512);
    const half8* wsrc_h = (const half8*)whp + (size_t)band_w * (8 * 512);
    const half8* wsrc_l = (const half8*)wlp + (size_t)band_w * (8 * 512);

    // fragment offsets (halfs): fo(row, q) = (row*4 + (q ^ (col>>2)))*8,
    // since (row>>2)&3 == (col>>2) for row = 16*i + col (+64-mult offsets).
    const int pa = quad ^ (col >> 2);

    float4v acc[4][4];
#pragma unroll
    for (int i = 0; i < 4; i++)
#pragma unroll
        for (int j = 0; j < 4; j++) acc[i][j] = (float4v){0.f, 0.f, 0.f, 0.f};

    for (int kt = 0; kt < NTILES; kt++) {
        __syncthreads();               // previous tile fully consumed
        const size_t tg = (size_t)kt * 512 + gbase + lane;   // per-lane granule
#pragma unroll
        for (int r = 0; r < 2; r++) {
            async_load16((const _Float16*)(xsrc_h + tg + 256 * r), xh + (gbase + 256 * r) * 8);
            async_load16((const _Float16*)(xsrc_l + tg + 256 * r), xl + (gbase + 256 * r) * 8);
            async_load16((const _Float16*)(wsrc_h + tg + 256 * r), wh + (gbase + 256 * r) * 8);
            async_load16((const _Float16*)(wsrc_l + tg + 256 * r), wl + (gbase + 256 * r) * 8);
        }
        __syncthreads();               // vmcnt(0) drained before barrier

        half8 ah[4], al[4];
#pragma unroll
        for (int i = 0; i < 4; i++) {
            const int off = ((wbb + 16 * i + col) * 4 + pa) * 8;
            ah[i] = *(const half8*)&xh[off];
            al[i] = *(const half8*)&xl[off];
        }
#pragma unroll
        for (int j = 0; j < 4; j++) {
            const int off = ((whh + 16 * j + col) * 4 + pa) * 8;
            half8 bh = *(const half8*)&wh[off];
            half8 bl = *(const half8*)&wl[off];
#pragma unroll
            for (int i = 0; i < 4; i++) {
                acc[i][j] = __builtin_amdgcn_mfma_f32_16x16x32_f16(ah[i], bh, acc[i][j], 0, 0, 0);
                acc[i][j] = __builtin_amdgcn_mfma_f32_16x16x32_f16(ah[i], bl, acc[i][j], 0, 0, 0);
                acc[i][j] = __builtin_amdgcn_mfma_f32_16x16x32_f16(al[i], bh, acc[i][j], 0, 0, 0);
            }
        }
    }

    // ---- stage breakpoints: bpl[k][128] ----
    __syncthreads();
    float* bpl = (float*)lds;          // 12.8 KB
    for (int n = tid; n < NSTEPS * 128; n += 256)
        bpl[n] = bp[(n >> 7) * NH + h0 + (n & 127)];
    __syncthreads();

    // ---- staircase: cnt = #{k : x1 >= c_k} ----
    float part[16];
#pragma unroll
    for (int e = 0; e < 16; e++) part[e] = 0.f;

#pragma unroll
    for (int j = 0; j < 4; j++) {
        const int hl = whh + 16 * j + col;
        const int h = h0 + hl;
        const float w2 = W2[h];
        const float bj = b1[h];
        float x1[16];
        int cnt[16];
#pragma unroll
        for (int e = 0; e < 16; e++) {
            x1[e] = acc[e >> 2][j][e & 3] + bj;
            cnt[e] = 0;
        }
#pragma unroll
        for (int k = 0; k < NSTEPS; k++) {
            const float c = bpl[k * 128 + hl];
#pragma unroll
            for (int e = 0; e < 16; e++) cnt[e] += (x1[e] >= c) ? 1 : 0;
        }
#pragma unroll
        for (int e = 0; e < 16; e++)
            part[e] = fmaf((float)cnt[e], w2, part[e]);
    }

    // ---- block reduction, one atomic per b-row ----
    __syncthreads();
    float* red = (float*)lds;          // 128*33 floats = 16.9 KB
#pragma unroll
    for (int e = 0; e < 16; e++) {
        const int row = wbb + 16 * (e >> 2) + 4 * quad + (e & 3);
        red[row * 33 + (w & 1) * 16 + col] = part[e];
    }
    __syncthreads();
    if (tid < BT) {
        float s = 0.f;
#pragma unroll
        for (int c = 0; c < 32; c++) s += red[tid * 33 + c];
        atomicAdd(&out[b0 + tid], s);
    }
}

// ===================== fallback path (R6, ws too small) =====================

__global__ __launch_bounds__(256) void snn_prep_small(
    const float* __restrict__ thr, const float* __restrict__ betap,
    const float* __restrict__ b2, float* __restrict__ out,
    float* __restrict__ bp, int B)
{
    const int tid = threadIdx.x;
    int bid = blockIdx.x;
    if (bid < 100) {
        const int idx = bid * 256 + tid;
        const int h = idx / NSTEPS;
        const int k = idx % NSTEPS + 1;
        const float th = thr[h];
        float beta = betap[0];
        beta = beta < 0.f ? 0.f : (beta > 1.f ? 1.f : beta);
        unsigned lo = f2k(-3.0e38f), hi = f2k(3.0e38f);
        float res;
        if (lif_count(k2f(hi), beta, th) < k) res = 3.0e38f;
        else if (lif_count(k2f(lo), beta, th) >= k) res = -3.0e38f;
        else {
#pragma unroll 1
            for (int it = 0; it < 32; it++) {
                unsigned mid = lo + ((hi - lo) >> 1);
                if (lif_count(k2f(mid), beta, th) >= k) hi = mid; else lo = mid;
            }
            res = k2f(hi);
        }
        bp[(k - 1) * NH + h] = res;
        return;
    }
    bid -= 100;
    const int i = bid * 256 + tid;
    if (i < B) out[i] = b2[0];
}

__global__ __launch_bounds__(256, 3) void snn_main_fb(
    const float* __restrict__ x, const float* __restrict__ W1,
    const float* __restrict__ b1, const float* __restrict__ W2,
    const float* __restrict__ bp, float* __restrict__ out)
{
    __shared__ __align__(16) _Float16 lds[4 * BT * RW];
    _Float16* xh = lds;
    _Float16* xl = lds + BT * RW;
    _Float16* wh = lds + 2 * BT * RW;
    _Float16* wl = lds + 3 * BT * RW;

    const int tid  = threadIdx.x;
    const int w    = tid >> 6;
    const int lane = tid & 63;
    const int col  = lane & 15;
    const int quad = lane >> 4;
    const int wbb  = (w >> 1) * 64;
    const int whh  = (w & 1) * 64;
    const int b0 = blockIdx.x * BT;
    const int h0 = blockIdx.y * BT;

    float4v acc[4][4];
#pragma unroll
    for (int i = 0; i < 4; i++)
#pragma unroll
        for (int j = 0; j < 4; j++) acc[i][j] = (float4v){0.f, 0.f, 0.f, 0.f};

    const int r0 = tid >> 3;
    const int c4 = tid & 7;
    const float* xrow = x + (size_t)(b0 + r0) * NI + 4 * c4;
    const float* wrow = W1 + (size_t)(h0 + r0) * NI + 4 * c4;

    for (int kt = 0; kt < NTILES; kt++) {
        const int ko = kt * BK;
        float4v vx[4], vw[4];
#pragma unroll
        for (int p = 0; p < 4; p++) {
            vx[p] = *(const float4v*)(xrow + (size_t)(32 * p) * NI + ko);
            vw[p] = *(const float4v*)(wrow + (size_t)(32 * p) * NI + ko);
        }
        __syncthreads();
#pragma unroll
        for (int p = 0; p < 4; p++) {
            const int row = r0 + 32 * p;
            half4 hx, lx, hw, lw;
#pragma unroll
            for (int q = 0; q < 4; q++) {
                float v = vx[p][q];
                _Float16 h = (_Float16)v;
                hx[q] = h;
                lx[q] = (_Float16)(v - (float)h);
                v = vw[p][q];
                h = (_Float16)v;
                hw[q] = h;
                lw[q] = (_Float16)(v - (float)h);
            }
            *(half4*)&xh[row * RW + 4 * c4] = hx;
            *(half4*)&xl[row * RW + 4 * c4] = lx;
            *(half4*)&wh[row * RW + 4 * c4] = hw;
            *(half4*)&wl[row * RW + 4 * c4] = lw;
        }
        __syncthreads();

        half8 ah[4], al[4];
#pragma unroll
        for (int i = 0; i < 4; i++) {
            ah[i] = *(const half8*)&xh[(wbb + 16 * i + col) * RW + 8 * quad];
            al[i] = *(const half8*)&xl[(wbb + 16 * i + col) * RW + 8 * quad];
        }
#pragma unroll
        for (int j = 0; j < 4; j++) {
            half8 bh = *(const half8*)&wh[(whh + 16 * j + col) * RW + 8 * quad];
            half8 bl = *(const half8*)&wl[(whh + 16 * j + col) * RW + 8 * quad];
#pragma unroll
            for (int i = 0; i < 4; i++) {
                acc[i][j] = __builtin_amdgcn_mfma_f32_16x16x32_f16(ah[i], bh, acc[i][j], 0, 0, 0);
                acc[i][j] = __builtin_amdgcn_mfma_f32_16x16x32_f16(ah[i], bl, acc[i][j], 0, 0, 0);
                acc[i][j] = __builtin_amdgcn_mfma_f32_16x16x32_f16(al[i], bh, acc[i][j], 0, 0, 0);
            }
        }
    }

    __syncthreads();
    float* bpl = (float*)lds;
    for (int n = tid; n < NSTEPS * 128; n += 256)
        bpl[n] = bp[(n >> 7) * NH + h0 + (n & 127)];
    __syncthreads();

    float part[16];
#pragma unroll
    for (int e = 0; e < 16; e++) part[e] = 0.f;
#pragma unroll
    for (int j = 0; j < 4; j++) {
        const int hl = whh + 16 * j + col;
        const int h = h0 + hl;
        const float w2 = W2[h];
        const float bj = b1[h];
        float x1[16];
        int cnt[16];
#pragma unroll
        for (int e = 0; e < 16; e++) {
            x1[e] = acc[e >> 2][j][e & 3] + bj;
            cnt[e] = 0;
        }
#pragma unroll
        for (int k = 0; k < NSTEPS; k++) {
            const float c = bpl[k * 128 + hl];
#pragma unroll
            for (int e = 0; e < 16; e++) cnt[e] += (x1[e] >= c) ? 1 : 0;
        }
#pragma unroll
        for (int e = 0; e < 16; e++)
            part[e] = fmaf((float)cnt[e], w2, part[e]);
    }

    __syncthreads();
    float* red = (float*)lds;
#pragma unroll
    for (int e = 0; e < 16; e++) {
        const int row = wbb + 16 * (e >> 2) + 4 * quad + (e & 3);
        red[row * 33 + (w & 1) * 16 + col] = part[e];
    }
    __syncthreads();
    if (tid < BT) {
        float s = 0.f;
#pragma unroll
        for (int c = 0; c < 32; c++) s += red[tid * 33 + c];
        atomicAdd(&out[b0 + tid], s);
    }
}

extern "C" void kernel_launch(void* const* d_in, const int* in_sizes, int n_in,
                              void* d_out, int out_size, void* d_ws, size_t ws_size,
                              hipStream_t stream) {
    const float* x    = (const float*)d_in[0];
    const float* W1   = (const float*)d_in[1];
    const float* b1   = (const float*)d_in[2];
    const float* W2   = (const float*)d_in[3];
    const float* b2   = (const float*)d_in[4];
    const float* beta = (const float*)d_in[5];
    const float* thr  = (const float*)d_in[6];
    float* out = (float*)d_out;

    const int B = in_sizes[0] / NI;  // 32768

    // ws layout: bp | wh | wl | xh | xl
    char* ws = (char*)d_ws;
    float*     bp  = (float*)ws;
    size_t off = (size_t)NH * NSTEPS * 4;            // 102400
    _Float16* whp = (_Float16*)(ws + off);  off += (size_t)NH * NI * 2;
    _Float16* wlp = (_Float16*)(ws + off);  off += (size_t)NH * NI * 2;
    _Float16* xhp = (_Float16*)(ws + off);  off += (size_t)B * NI * 2;
    _Float16* xlp = (_Float16*)(ws + off);  off += (size_t)B * NI * 2;
    const size_t ws_need = off;

    if (ws_size >= ws_need) {
        const int nblk = B / 8 + 128 + 100 + (B + 255) / 256;
        snn_prep<<<nblk, 256, 0, stream>>>(x, W1, thr, beta, b2, out,
                                           bp, whp, wlp, xhp, xlp, B);
        dim3 grid(B / BT, NH / BT);
        snn_main_fast<<<grid, 256, 0, stream>>>(xhp, xlp, whp, wlp, b1, W2, bp, out);
    } else {
        snn_prep_small<<<100 + (B + 255) / 256, 256, 0, stream>>>(thr, beta, b2, out, bp, B);
        dim3 grid(B / BT, NH / BT);
        snn_main_fb<<<grid, 256, 0, stream>>>(x, W1, b1, W2, bp, out);
    }
}

// Round 8
// 168.714 us; speedup vs baseline: 1.1151x; 1.1151x over previous
//
#include <hip/hip_runtime.h>

// LeakySNN fused: out[b] = b2 + sum_h spksum(x1[b,h]) * W2[h]
// R8: (1) fragment-direct GEMM — prep writes xh/xl/wh/wl in exact MFMA
//     fragment granule order, so the main kernel loads A/B frags straight
//     from global (L2-hot) to registers: no LDS staging, no ds_read_b128,
//     and ZERO __syncthreads in the K-loop (kills the vmcnt(0) barrier
//     drains). (2) staircase count via 5-level branch-free binary search
//     (c_k nondecreasing in k) over LDS breakpoints with row stride 132
//     (= 4 mod 32 banks -> conflict-free divergent reads): ~24 issue
//     slots/elem vs ~52 linear.

#define NI 256
#define NH 1024
#define NSTEPS 25
#define BT 128
#define BK 32
#define NTILES (NI / BK)
#define BPROW 132     // bpl row stride in floats; 132 % 32 == 4
#define RW 40         // fallback (R6) LDS row width in halfs

typedef _Float16 half8 __attribute__((ext_vector_type(8)));
typedef _Float16 half4 __attribute__((ext_vector_type(4)));
typedef float float4v __attribute__((ext_vector_type(4)));

__device__ __forceinline__ unsigned f2k(float f) {
    unsigned u = __float_as_uint(f);
    return (u >> 31) ? ~u : (u | 0x80000000u);
}
__device__ __forceinline__ float k2f(unsigned k) {
    unsigned u = (k & 0x80000000u) ? (k & 0x7FFFFFFFu) : ~k;
    return __uint_as_float(u);
}

// 25-step LIF count, exact reference-matching arithmetic (R4/R6).
__device__ __forceinline__ int lif_count(float x1, float beta, float th) {
    float mem = 0.f;
    float spk = (0.f > th) ? 1.f : 0.f;
    int c = 0;
#pragma unroll
    for (int t = 0; t < NSTEPS; t++) {
        mem = fmaf(spk, -th, fmaf(beta, mem, x1));
        spk = (mem > th) ? 1.f : 0.f;
        c += (mem > th);
    }
    return c;
}

__device__ __forceinline__ void split8(const float* src, half8* hi, half8* lo) {
    float4v a = *(const float4v*)src;
    float4v b = *(const float4v*)(src + 4);
#pragma unroll
    for (int e = 0; e < 4; e++) {
        _Float16 h = (_Float16)a[e];
        (*hi)[e] = h;
        (*lo)[e] = (_Float16)(a[e] - (float)h);
        h = (_Float16)b[e];
        (*hi)[e + 4] = h;
        (*lo)[e + 4] = (_Float16)(b[e] - (float)h);
    }
}

// ===================== fast path =====================

// Granule layout (8 halfs = one MFMA k-chunk of one row):
//   G = band*4096 + kt*512 + r8*64 + quad*16 + col
//   holds src[row = band*128 + r8*16 + col][k = kt*32 + quad*8 .. +8]
// Main-kernel frag load for lane (col,quad) is granule r8*64+quad*16+col ->
// 16 B/lane, consecutive cols contiguous => perfectly coalesced dwordx4.
__global__ __launch_bounds__(256) void snn_prep(
    const float* __restrict__ x, const float* __restrict__ W1,
    const float* __restrict__ thr, const float* __restrict__ betap,
    const float* __restrict__ b2, float* __restrict__ out,
    float* __restrict__ bp, _Float16* __restrict__ whp, _Float16* __restrict__ wlp,
    _Float16* __restrict__ xhp, _Float16* __restrict__ xlp, int B)
{
    const int tid = threadIdx.x;
    const int XB = B / 8;            // x granules / 256
    int bid = blockIdx.x;

    if (bid < XB) {                  // ---- x split ----
        const int G = bid * 256 + tid;
        const int band = G >> 12;
        const int rem = G & 4095;
        const int kt = rem >> 9;
        const int rem2 = rem & 511;
        const int r8 = rem2 >> 6, quad = (rem2 >> 4) & 3, col = rem2 & 15;
        const float* src = x + (size_t)(band * 128 + r8 * 16 + col) * NI + kt * 32 + quad * 8;
        half8 hi, lo;
        split8(src, &hi, &lo);
        ((half8*)xhp)[G] = hi;
        ((half8*)xlp)[G] = lo;
        return;
    }
    bid -= XB;
    if (bid < 128) {                 // ---- W1 split ----
        const int G = bid * 256 + tid;   // < 32768
        const int band = G >> 12;
        const int rem = G & 4095;
        const int kt = rem >> 9;
        const int rem2 = rem & 511;
        const int r8 = rem2 >> 6, quad = (rem2 >> 4) & 3, col = rem2 & 15;
        const float* src = W1 + (size_t)(band * 128 + r8 * 16 + col) * NI + kt * 32 + quad * 8;
        half8 hi, lo;
        split8(src, &hi, &lo);
        ((half8*)whp)[G] = hi;
        ((half8*)wlp)[G] = lo;
        return;
    }
    bid -= 128;
    if (bid < 100) {                 // ---- breakpoints ----
        const int idx = bid * 256 + tid;     // exactly 25600
        const int h = idx / NSTEPS;
        const int k = idx % NSTEPS + 1;      // target count 1..25
        const float th = thr[h];
        float beta = betap[0];
        beta = beta < 0.f ? 0.f : (beta > 1.f ? 1.f : beta);
        unsigned lo = f2k(-3.0e38f), hi = f2k(3.0e38f);
        float res;
        if (lif_count(k2f(hi), beta, th) < k) {
            res = 3.0e38f;
        } else if (lif_count(k2f(lo), beta, th) >= k) {
            res = -3.0e38f;
        } else {
#pragma unroll 1
            for (int it = 0; it < 32; it++) {
                unsigned mid = lo + ((hi - lo) >> 1);
                if (lif_count(k2f(mid), beta, th) >= k) hi = mid; else lo = mid;
            }
            res = k2f(hi);
        }
        bp[(k - 1) * NH + h] = res;
        return;
    }
    bid -= 100;
    {                                // ---- out init ----
        const int i = bid * 256 + tid;
        if (i < B) out[i] = b2[0];
    }
}

__global__ __launch_bounds__(256, 2) void snn_main_fast(
    const _Float16* __restrict__ xhp, const _Float16* __restrict__ xlp,
    const _Float16* __restrict__ whp, const _Float16* __restrict__ wlp,
    const float* __restrict__ b1, const float* __restrict__ W2,
    const float* __restrict__ bp, float* __restrict__ out)
{
    __shared__ float smem[128 * 33];   // 16.9 KB: bpl (31*132=4092) then red

    const int tid  = threadIdx.x;
    const int w    = tid >> 6;
    const int lane = tid & 63;
    const int col  = lane & 15;
    const int quad = lane >> 4;
    const int wbb  = (w >> 1) * 64;
    const int whh  = (w & 1) * 64;
    const int r8x0 = (w >> 1) * 4;     // x r8 base
    const int r8w0 = (w & 1) * 4;      // w r8 base
    const int bband = blockIdx.x;
    const int hband = blockIdx.y;
    const int b0 = bband * BT;
    const int h0 = hband * BT;
    const int loff = quad * 16 + col;

    const half8* xh = (const half8*)xhp + (size_t)bband * 4096;
    const half8* xl = (const half8*)xlp + (size_t)bband * 4096;
    const half8* wh = (const half8*)whp + (size_t)hband * 4096;
    const half8* wl = (const half8*)wlp + (size_t)hband * 4096;

    float4v acc[4][4];
#pragma unroll
    for (int i = 0; i < 4; i++)
#pragma unroll
        for (int j = 0; j < 4; j++) acc[i][j] = (float4v){0.f, 0.f, 0.f, 0.f};

    // ---- GEMM: fragment-direct loads, no LDS, no barriers ----
#pragma unroll 2
    for (int kt = 0; kt < NTILES; kt++) {
        const int xi = kt * 512 + r8x0 * 64 + loff;
        const int wi = kt * 512 + r8w0 * 64 + loff;
        half8 ah[4], al[4], bh[4], bl[4];
#pragma unroll
        for (int i = 0; i < 4; i++) {
            ah[i] = xh[xi + i * 64];
            al[i] = xl[xi + i * 64];
        }
#pragma unroll
        for (int j = 0; j < 4; j++) {
            bh[j] = wh[wi + j * 64];
            bl[j] = wl[wi + j * 64];
        }
#pragma unroll
        for (int j = 0; j < 4; j++)
#pragma unroll
            for (int i = 0; i < 4; i++) {
                acc[i][j] = __builtin_amdgcn_mfma_f32_16x16x32_f16(ah[i], bh[j], acc[i][j], 0, 0, 0);
                acc[i][j] = __builtin_amdgcn_mfma_f32_16x16x32_f16(ah[i], bl[j], acc[i][j], 0, 0, 0);
                acc[i][j] = __builtin_amdgcn_mfma_f32_16x16x32_f16(al[i], bh[j], acc[i][j], 0, 0, 0);
            }
    }

    // ---- stage breakpoints: bpl[t][hl], t=0..30 holds c_{t+1} (pad=+inf) ----
    float* bpl = smem;
    for (int n = tid; n < 31 * 128; n += 256) {
        const int t = n >> 7, hl = n & 127;
        bpl[t * BPROW + hl] = (t < NSTEPS) ? bp[t * NH + h0 + hl] : 3.0e38f;
    }
    __syncthreads();

    // ---- count via binary search: m = max{k: x1 >= c_k} (c_k sorted) ----
    float part[16];
#pragma unroll
    for (int e = 0; e < 16; e++) part[e] = 0.f;

#pragma unroll
    for (int j = 0; j < 4; j++) {
        const int hl = whh + 16 * j + col;
        const int h = h0 + hl;
        const float w2 = W2[h];
        const float bj = b1[h];
        const float* pj = bpl + hl;
        float x1[16];
        int mo[16];                      // m * BPROW (float units)
#pragma unroll
        for (int e = 0; e < 16; e++) {
            x1[e] = acc[e >> 2][j][e & 3] + bj;
            mo[e] = 0;
        }
#pragma unroll
        for (int bstep = 16; bstep >= 1; bstep >>= 1) {
#pragma unroll
            for (int e = 0; e < 16; e++) {
                // row m+bstep-1 holds c_{m+bstep}
                const float c = pj[mo[e] + (bstep - 1) * BPROW];
                mo[e] += (x1[e] >= c) ? bstep * BPROW : 0;
            }
        }
#pragma unroll
        for (int e = 0; e < 16; e++) {
            const float cntf = (float)mo[e] * (1.0f / BPROW);   // exact ints / 132
            part[e] = fmaf(cntf, w2, part[e]);
        }
    }

    // ---- block reduction, one atomic per b-row ----
    __syncthreads();                   // bpl dead
    float* red = smem;                 // 128 x 33
#pragma unroll
    for (int e = 0; e < 16; e++) {
        const int row = wbb + 16 * (e >> 2) + 4 * quad + (e & 3);
        red[row * 33 + (w & 1) * 16 + col] = part[e];
    }
    __syncthreads();
    if (tid < BT) {
        float s = 0.f;
#pragma unroll
        for (int c = 0; c < 32; c++) s += red[tid * 33 + c];
        atomicAdd(&out[b0 + tid], s);
    }
}

// ===================== fallback path (R6-style, ws too small) =====================

__global__ __launch_bounds__(256) void snn_prep_small(
    const float* __restrict__ thr, const float* __restrict__ betap,
    const float* __restrict__ b2, float* __restrict__ out,
    float* __restrict__ bp, int B)
{
    const int tid = threadIdx.x;
    int bid = blockIdx.x;
    if (bid < 100) {
        const int idx = bid * 256 + tid;
        const int h = idx / NSTEPS;
        const int k = idx % NSTEPS + 1;
        const float th = thr[h];
        float beta = betap[0];
        beta = beta < 0.f ? 0.f : (beta > 1.f ? 1.f : beta);
        unsigned lo = f2k(-3.0e38f), hi = f2k(3.0e38f);
        float res;
        if (lif_count(k2f(hi), beta, th) < k) res = 3.0e38f;
        else if (lif_count(k2f(lo), beta, th) >= k) res = -3.0e38f;
        else {
#pragma unroll 1
            for (int it = 0; it < 32; it++) {
                unsigned mid = lo + ((hi - lo) >> 1);
                if (lif_count(k2f(mid), beta, th) >= k) hi = mid; else lo = mid;
            }
            res = k2f(hi);
        }
        bp[(k - 1) * NH + h] = res;
        return;
    }
    bid -= 100;
    const int i = bid * 256 + tid;
    if (i < B) out[i] = b2[0];
}

__global__ __launch_bounds__(256, 3) void snn_main_fb(
    const float* __restrict__ x, const float* __restrict__ W1,
    const float* __restrict__ b1, const float* __restrict__ W2,
    const float* __restrict__ bp, float* __restrict__ out)
{
    __shared__ __align__(16) _Float16 lds[4 * BT * RW];
    _Float16* xh = lds;
    _Float16* xl = lds + BT * RW;
    _Float16* wh = lds + 2 * BT * RW;
    _Float16* wl = lds + 3 * BT * RW;

    const int tid  = threadIdx.x;
    const int w    = tid >> 6;
    const int lane = tid & 63;
    const int col  = lane & 15;
    const int quad = lane >> 4;
    const int wbb  = (w >> 1) * 64;
    const int whh  = (w & 1) * 64;
    const int b0 = blockIdx.x * BT;
    const int h0 = blockIdx.y * BT;

    float4v acc[4][4];
#pragma unroll
    for (int i = 0; i < 4; i++)
#pragma unroll
        for (int j = 0; j < 4; j++) acc[i][j] = (float4v){0.f, 0.f, 0.f, 0.f};

    const int r0 = tid >> 3;
    const int c4 = tid & 7;
    const float* xrow = x + (size_t)(b0 + r0) * NI + 4 * c4;
    const float* wrow = W1 + (size_t)(h0 + r0) * NI + 4 * c4;

    for (int kt = 0; kt < NTILES; kt++) {
        const int ko = kt * BK;
        float4v vx[4], vw[4];
#pragma unroll
        for (int p = 0; p < 4; p++) {
            vx[p] = *(const float4v*)(xrow + (size_t)(32 * p) * NI + ko);
            vw[p] = *(const float4v*)(wrow + (size_t)(32 * p) * NI + ko);
        }
        __syncthreads();
#pragma unroll
        for (int p = 0; p < 4; p++) {
            const int row = r0 + 32 * p;
            half4 hx, lx, hw, lw;
#pragma unroll
            for (int q = 0; q < 4; q++) {
                float v = vx[p][q];
                _Float16 h = (_Float16)v;
                hx[q] = h;
                lx[q] = (_Float16)(v - (float)h);
                v = vw[p][q];
                h = (_Float16)v;
                hw[q] = h;
                lw[q] = (_Float16)(v - (float)h);
            }
            *(half4*)&xh[row * RW + 4 * c4] = hx;
            *(half4*)&xl[row * RW + 4 * c4] = lx;
            *(half4*)&wh[row * RW + 4 * c4] = hw;
            *(half4*)&wl[row * RW + 4 * c4] = lw;
        }
        __syncthreads();

        half8 ah[4], al[4];
#pragma unroll
        for (int i = 0; i < 4; i++) {
            ah[i] = *(const half8*)&xh[(wbb + 16 * i + col) * RW + 8 * quad];
            al[i] = *(const half8*)&xl[(wbb + 16 * i + col) * RW + 8 * quad];
        }
#pragma unroll
        for (int j = 0; j < 4; j++) {
            half8 bh = *(const half8*)&wh[(whh + 16 * j + col) * RW + 8 * quad];
            half8 bl = *(const half8*)&wl[(whh + 16 * j + col) * RW + 8 * quad];
#pragma unroll
            for (int i = 0; i < 4; i++) {
                acc[i][j] = __builtin_amdgcn_mfma_f32_16x16x32_f16(ah[i], bh, acc[i][j], 0, 0, 0);
                acc[i][j] = __builtin_amdgcn_mfma_f32_16x16x32_f16(ah[i], bl, acc[i][j], 0, 0, 0);
                acc[i][j] = __builtin_amdgcn_mfma_f32_16x16x32_f16(al[i], bh, acc[i][j], 0, 0, 0);
            }
        }
    }

    __syncthreads();
    float* bpl = (float*)lds;
    for (int n = tid; n < NSTEPS * 128; n += 256)
        bpl[n] = bp[(n >> 7) * NH + h0 + (n & 127)];
    __syncthreads();

    float part[16];
#pragma unroll
    for (int e = 0; e < 16; e++) part[e] = 0.f;
#pragma unroll
    for (int j = 0; j < 4; j++) {
        const int hl = whh + 16 * j + col;
        const int h = h0 + hl;
        const float w2 = W2[h];
        const float bj = b1[h];
        float x1[16];
        int cnt[16];
#pragma unroll
        for (int e = 0; e < 16; e++) {
            x1[e] = acc[e >> 2][j][e & 3] + bj;
            cnt[e] = 0;
        }
#pragma unroll
        for (int k = 0; k < NSTEPS; k++) {
            const float c = bpl[k * 128 + hl];
#pragma unroll
            for (int e = 0; e < 16; e++) cnt[e] += (x1[e] >= c) ? 1 : 0;
        }
#pragma unroll
        for (int e = 0; e < 16; e++)
            part[e] = fmaf((float)cnt[e], w2, part[e]);
    }

    __syncthreads();
    float* red = (float*)lds;
#pragma unroll
    for (int e = 0; e < 16; e++) {
        const int row = wbb + 16 * (e >> 2) + 4 * quad + (e & 3);
        red[row * 33 + (w & 1) * 16 + col] = part[e];
    }
    __syncthreads();
    if (tid < BT) {
        float s = 0.f;
#pragma unroll
        for (int c = 0; c < 32; c++) s += red[tid * 33 + c];
        atomicAdd(&out[b0 + tid], s);
    }
}

extern "C" void kernel_launch(void* const* d_in, const int* in_sizes, int n_in,
                              void* d_out, int out_size, void* d_ws, size_t ws_size,
                              hipStream_t stream) {
    const float* x    = (const float*)d_in[0];
    const float* W1   = (const float*)d_in[1];
    const float* b1   = (const float*)d_in[2];
    const float* W2   = (const float*)d_in[3];
    const float* b2   = (const float*)d_in[4];
    const float* beta = (const float*)d_in[5];
    const float* thr  = (const float*)d_in[6];
    float* out = (float*)d_out;

    const int B = in_sizes[0] / NI;  // 32768

    // ws layout: bp | wh | wl | xh | xl
    char* ws = (char*)d_ws;
    float*     bp  = (float*)ws;
    size_t off = (size_t)NH * NSTEPS * 4;            // 102400
    _Float16* whp = (_Float16*)(ws + off);  off += (size_t)NH * NI * 2;
    _Float16* wlp = (_Float16*)(ws + off);  off += (size_t)NH * NI * 2;
    _Float16* xhp = (_Float16*)(ws + off);  off += (size_t)B * NI * 2;
    _Float16* xlp = (_Float16*)(ws + off);  off += (size_t)B * NI * 2;
    const size_t ws_need = off;

    if (ws_size >= ws_need) {
        const int nblk = B / 8 + 128 + 100 + (B + 255) / 256;
        snn_prep<<<nblk, 256, 0, stream>>>(x, W1, thr, beta, b2, out,
                                           bp, whp, wlp, xhp, xlp, B);
        dim3 grid(B / BT, NH / BT);
        snn_main_fast<<<grid, 256, 0, stream>>>(xhp, xlp, whp, wlp, b1, W2, bp, out);
    } else {
        snn_prep_small<<<100 + (B + 255) / 256, 256, 0, stream>>>(thr, beta, b2, out, bp, B);
        dim3 grid(B / BT, NH / BT);
        snn_main_fb<<<grid, 256, 0, stream>>>(x, W1, b1, W2, bp, out);
    }
}